// Round 5
// baseline (142.802 us; speedup 1.0000x reference)
//
#include <hip/hip_runtime.h>
#include <hip/hip_bf16.h>

// 3D conv K=2 VALID + (y+1)^2 via mfma_f32_32x32x16_bf16, d-rolling LDS.
// x: (8,16,64,64,64) f32; w: (32,128) f32, k = c*8 + kd*4 + kh*2 + kw.
// out: (8,32,63,63,63) f32.
//
// R4 compute structure kept: K permuted to k' = tap*16 + c, LDS slab
// [h9][w64][c16] bf16, one ds_read_b128 per B-fragment, D cols = 32-lane
// w-runs -> 128-B store segments. New in R5:
//  - block owns 4 d-outputs with a 2-slab rolling double buffer: 5 slabs
//    staged per 4 outputs (was 2 per 1), weights loaded once per 4 d.
//  - T14 split staging: 36 prefetch loads issued as one batch BEFORE
//    compute (latency hides under MFMA+stores), cvt+ds_write after barrier.
//  - weight fetch = 16x f32x4 contiguous per lane (was 64 scalar loads).
// grid = 8 h-tiles x 16 d-chunks x 8 b = 1024 blocks = 4/CU, no tail.

typedef __attribute__((ext_vector_type(8)))  short short8;
typedef __attribute__((ext_vector_type(4)))  float f32x4;
typedef __attribute__((ext_vector_type(16))) float f32x16;
typedef __attribute__((ext_vector_type(4)))  unsigned short u16x4;

#define XCS 262144        // 64^3 x channel stride (f32)
#define OS  250047        // 63^3 out channel stride (f32)
#define SLAB_E 9216       // 9*64*16 u16 per d-slab

__device__ __forceinline__ unsigned short f2bf(float f) {
    unsigned int u = __builtin_bit_cast(unsigned int, f);
    return (unsigned short)((u + 0x7fffu + ((u >> 16) & 1u)) >> 16);
}

__global__ __launch_bounds__(256, 4) void conv3d_k2_roll32(
    const float* __restrict__ x,
    const float* __restrict__ wgt,
    float* __restrict__ out)
{
    __shared__ unsigned short tile[2 * SLAB_E + 32];   // 36,928 B

    const int t   = threadIdx.x;
    const int l   = t & 63;
    const int wv  = t >> 6;        // wave 0..3
    const int col = l & 31;        // MFMA col (w) / A row (o)
    const int kh8 = l >> 5;        // k-half -> c-half

    const int h0 = blockIdx.x * 8; // 8 output h rows
    const int d0 = blockIdx.y * 4; // 4 output d (3 in last chunk)
    const int b  = blockIdx.z;
    const int nd = (63 - d0 < 4) ? (63 - d0) : 4;

    // ---- A fragments: 64 contiguous floats per lane, compile-time shuffle ----
    short8 aF[8];
    {
        f32x4 wreg[16];
        const float* wp = wgt + col * 128 + kh8 * 64;
#pragma unroll
        for (int q = 0; q < 16; ++q) wreg[q] = *(const f32x4*)(wp + q * 4);
#pragma unroll
        for (int tap = 0; tap < 8; ++tap) {
            short8 a;
#pragma unroll
            for (int j = 0; j < 8; ++j) {
                const int k = j * 8 + tap;          // k within c-half block
                a[j] = (short)f2bf(wreg[k >> 2][k & 3]);
            }
            aF[tap] = a;
        }
    }

    // ---- staging geometry: thread (sw = t&63 = w, cq = t>>6 = c-quad) ----
    const int sw = t & 63;
    const int cq = t >> 6;
    const float* xb = x + (size_t)b * 16 * XCS;

    // prologue: stage slabs d0 -> buf0, d0+1 -> buf1 (batched loads)
#pragma unroll
    for (int p = 0; p < 2; ++p) {
        const float* xs = xb + (size_t)(d0 + p) * 4096;
        float v[9][4];
#pragma unroll
        for (int h = 0; h < 9; ++h) {
            int hp = h0 + h; if (hp > 63) hp = 63;
#pragma unroll
            for (int i = 0; i < 4; ++i)
                v[h][i] = xs[(size_t)(cq * 4 + i) * XCS + hp * 64 + sw];
        }
#pragma unroll
        for (int h = 0; h < 9; ++h) {
            u16x4 pk;
#pragma unroll
            for (int i = 0; i < 4; ++i) pk[i] = f2bf(v[h][i]);
            *(u16x4*)&tile[p * SLAB_E + h * 1024 + sw * 16 + cq * 4] = pk;
        }
    }
    __syncthreads();

    for (int dd = 0; dd < nd; ++dd) {
        const bool doPre = (dd + 1) < nd;

        // T14: issue next slab's 36 loads now; consume after compute
        float pre[9][4];
        if (doPre) {
            const float* xs = xb + (size_t)(d0 + dd + 2) * 4096;
#pragma unroll
            for (int h = 0; h < 9; ++h) {
                int hp = h0 + h; if (hp > 63) hp = 63;
#pragma unroll
                for (int i = 0; i < 4; ++i)
                    pre[h][i] = xs[(size_t)(cq * 4 + i) * XCS + hp * 64 + sw];
            }
        }

        const int pA = (dd & 1) * SLAB_E;        // slab d0+dd   (kd=0)
        const int pB = ((dd + 1) & 1) * SLAB_E;  // slab d0+dd+1 (kd=1)
#pragma unroll
        for (int th = 0; th < 2; ++th) {
            const int hl = wv * 2 + th;
#pragma unroll
            for (int wh = 0; wh < 2; ++wh) {
                const int wb = wh * 32;
                f32x16 acc = {};
#pragma unroll
                for (int kd = 0; kd < 2; ++kd)
#pragma unroll
                for (int kh = 0; kh < 2; ++kh)
#pragma unroll
                for (int kw = 0; kw < 2; ++kw) {
                    const int tap = kd * 4 + kh * 2 + kw;
                    short8 bfrag = *(const short8*)&tile[(kd ? pB : pA)
                        + (hl + kh) * 1024 + (wb + col + kw) * 16 + kh8 * 8];
                    acc = __builtin_amdgcn_mfma_f32_32x32x16_bf16(aF[tap], bfrag, acc, 0, 0, 0);
                }
                const int h  = h0 + hl;
                const int wc = wb + col;
                if (h < 63 && wc < 63) {
                    float* ob = out + (size_t)b * 32 * OS + (size_t)(d0 + dd) * 3969
                                    + h * 63 + wc;
#pragma unroll
                    for (int r = 0; r < 16; ++r) {
                        const int o = (r & 3) + 8 * (r >> 2) + 4 * kh8;
                        float y = acc[r] + 1.0f;
                        ob[(size_t)o * OS] = y * y;
                    }
                }
            }
        }

        __syncthreads();               // everyone done reading buf dd&1
        if (doPre) {
#pragma unroll
            for (int h = 0; h < 9; ++h) {
                u16x4 pk;
#pragma unroll
                for (int i = 0; i < 4; ++i) pk[i] = f2bf(pre[h][i]);
                *(u16x4*)&tile[(dd & 1) * SLAB_E + h * 1024 + sw * 16 + cq * 4] = pk;
            }
        }
        __syncthreads();
    }
}

extern "C" void kernel_launch(void* const* d_in, const int* in_sizes, int n_in,
                              void* d_out, int out_size, void* d_ws, size_t ws_size,
                              hipStream_t stream) {
    const float* x   = (const float*)d_in[0];
    const float* wgt = (const float*)d_in[1];
    float* out = (float*)d_out;

    dim3 grid(8, 16, 8);    // h-tiles, d-chunks, b
    dim3 block(256);
    conv3d_k2_roll32<<<grid, block, 0, stream>>>(x, wgt, out);
}